// Round 14
// baseline (268.953 us; speedup 1.0000x reference)
//
#include <hip/hip_runtime.h>

typedef unsigned short ushort_t;
typedef __attribute__((ext_vector_type(8))) short short8;
typedef __attribute__((ext_vector_type(4))) float floatx4;

constexpr int F = 256, H = 128, C = 16, HX = 64;
constexpr int NBCOL = H + HX; // 192 fused output cols of GEMM1

__device__ __forceinline__ ushort_t f2bf(float f) {
  unsigned u = __float_as_uint(f);
  u += 0x7fffu + ((u >> 16) & 1u);   // round-to-nearest-even
  return (ushort_t)(u >> 16);
}
__device__ __forceinline__ float bflo(unsigned u) { return __uint_as_float(u << 16); }
__device__ __forceinline__ float bfhi(unsigned u) { return __uint_as_float(u & 0xffff0000u); }

// ---- fat pre-kernel: conv_x(tile-major) | conv_w | count ----
// xb layout: 16B unit index = tile*512 + j*16 + l15  (j = k-chunk 0..31,
// l15 = row within tile) -> gemm1's wave load (kk,q) is one contiguous 1KB.
__global__ void k_pre(const float* __restrict__ x, ushort_t* __restrict__ xb, int totalU,
                      const float* __restrict__ W1, const float* __restrict__ Wx,
                      ushort_t* __restrict__ WBt,
                      const int* __restrict__ dst, int* __restrict__ deg, int e,
                      int n, int nbx, int nbw) {
  int b = blockIdx.x;
  if (b < nbx) {
    int i = b * 256 + threadIdx.x;   // 16B-unit index
    if (i >= totalU) return;
    int tile = i >> 9, rem = i & 511, j = rem >> 4, l15 = rem & 15;
    int row = tile * 16 + l15;
    ushort4 lo = make_ushort4(0, 0, 0, 0), hi = lo;
    if (row < n) {
      const float4* xp = (const float4*)(x + (size_t)row * F + j * 8);
      float4 a = xp[0], bb = xp[1];
      lo = make_ushort4(f2bf(a.x), f2bf(a.y), f2bf(a.z), f2bf(a.w));
      hi = make_ushort4(f2bf(bb.x), f2bf(bb.y), f2bf(bb.z), f2bf(bb.w));
    }
    ((ushort4*)xb)[2 * i] = lo;      // writes: perfectly coalesced
    ((ushort4*)xb)[2 * i + 1] = hi;
  } else if (b < nbx + nbw) {
    int i = (b - nbx) * 256 + threadIdx.x;
    if (i >= NBCOL * F) return;
    int nn = i / F, k = i % F;
    float v = (nn < H) ? W1[k * H + nn] : Wx[k * HX + (nn - H)];
    WBt[nn * F + k] = f2bf(v);
  } else {
    int i = (b - nbx - nbw) * 256 + threadIdx.x;
    if (i < e) atomicAdd(&deg[dst[i]], 1);
  }
}

// ---- single-kernel scan: each block self-computes offset = sum(deg[0..c*256))
// (<=50k coalesced int reads per block, L2-resident -> cheap), then produces
// row_start/cursor/dinv for its chunk. Replaces scan_a + scan_c.
__global__ void k_scan(const int* __restrict__ deg,
                       int* __restrict__ row_start, int* __restrict__ cursor,
                       float* __restrict__ dinv, int n, int e) {
  __shared__ int psm[256];
  __shared__ int wsum[4], woff[4];
  int c = blockIdx.x, t = threadIdx.x;
  int base = c * 256;
  int accs = 0;
  for (int i = t; i < base; i += 256) accs += deg[i];
  psm[t] = accs;
  __syncthreads();
  for (int s = 128; s > 0; s >>= 1) {
    if (t < s) psm[t] += psm[t + s];
    __syncthreads();
  }
  int blockoff = psm[0];
  __syncthreads();

  int i = base + t;
  int lane = t & 63, wid = t >> 6;
  int v = (i < n) ? deg[i] : 0;
  int xs = v;
  for (int d = 1; d < 64; d <<= 1) {
    int u = __shfl_up(xs, d);
    if (lane >= d) xs += u;
  }
  if (lane == 63) wsum[wid] = xs;
  __syncthreads();
  if (t == 0) {
    int s = 0;
    for (int w = 0; w < 4; w++) { woff[w] = s; s += wsum[w]; }
  }
  __syncthreads();
  int excl = xs - v + woff[wid] + blockoff;
  if (i < n) {
    row_start[i] = excl;
    cursor[i] = excl;
    dinv[i] = rsqrtf((float)(v + 1));  // +1 self-loop
  }
  if (i == 0) row_start[n] = e;
}

// ---- CSR fill: pack (src, dinv[src]) per edge slot ----
__global__ void k_fill(const int* __restrict__ src, const int* __restrict__ dst,
                       const float* __restrict__ dinv, int* __restrict__ cursor,
                       int2* __restrict__ csr8, int e) {
  int i = blockIdx.x * 256 + threadIdx.x;
  if (i < e) {
    int s = src[i];
    int p = atomicAdd(&cursor[dst[i]], 1);
    csr8[p] = make_int2(s, __float_as_int(dinv[s]));
  }
}

// ---- MFMA GEMM, register-resident B, tile-major bf16 xb input ----
// B = 192x256 bf16 = 96 KB = 24 short8/wave @48 cols/wave, hoisted once.
// A: tile-major xb -> each of the 8 per-tile loads is one contiguous 1KB
// wave segment. Total live ~160 VGPR fits (256,3). DO NOT read f32 x
// directly (R11: allocator sinks B, VGPR=72) and DO NOT merge into branchy
// fat kernels (R10: same collapse).
__global__ __launch_bounds__(256, 3) void k_gemm1(const ushort_t* __restrict__ xb,
                                                  const ushort_t* __restrict__ WBt,
                                                  const float* __restrict__ bx,
                                                  ushort_t* __restrict__ xw1,
                                                  float* __restrict__ xe,
                                                  int n, int ntiles) {
  int w = threadIdx.x >> 6, lane = threadIdx.x & 63;
  int q = lane >> 4, l15 = lane & 15;
  const short8* bb = (const short8*)WBt;
  short8 bfr[3][8];
#pragma unroll
  for (int t = 0; t < 3; t++)
#pragma unroll
    for (int kk = 0; kk < 8; kk++)
      bfr[t][kk] = bb[(size_t)(w * 48 + t * 16 + l15) * 32 + kk * 4 + q];

  float bxv[3];
#pragma unroll
  for (int t = 0; t < 3; t++) {
    int g = w * 48 + t * 16;
    bxv[t] = (g >= H) ? bx[g - H + l15] : 0.0f;
  }

  const short8* ab = (const short8*)xb;
  for (int tile = blockIdx.x; tile < ntiles; tile += gridDim.x) {
    const short8* atile = ab + (size_t)tile * 512;
    short8 a[8];
#pragma unroll
    for (int kk = 0; kk < 8; kk++) a[kk] = atile[kk * 64 + q * 16 + l15];

    floatx4 acc0 = (floatx4)(0.0f), acc1 = (floatx4)(0.0f), acc2 = (floatx4)(0.0f);
#pragma unroll
    for (int kk = 0; kk < 8; kk++) {
      acc0 = __builtin_amdgcn_mfma_f32_16x16x32_bf16(a[kk], bfr[0][kk], acc0, 0, 0, 0);
      acc1 = __builtin_amdgcn_mfma_f32_16x16x32_bf16(a[kk], bfr[1][kk], acc1, 0, 0, 0);
      acc2 = __builtin_amdgcn_mfma_f32_16x16x32_bf16(a[kk], bfr[2][kk], acc2, 0, 0, 0);
    }

    // C/D layout: col = lane&15, row = (lane>>4)*4 + r
    floatx4 accs[3] = {acc0, acc1, acc2};
    int rbase = tile * 16 + q * 4;
#pragma unroll
    for (int t = 0; t < 3; t++) {
      int g = w * 48 + t * 16;  // wave-uniform output col base
#pragma unroll
      for (int r = 0; r < 4; r++) {
        int ro = rbase + r;
        if (ro < n) {
          if (g < H) {
            xw1[(size_t)ro * H + g + l15] = f2bf(accs[t][r]);
          } else {
            xe[(size_t)ro * HX + (g - H) + l15] = fmaxf(accs[t][r] + bxv[t], 0.0f);
          }
        }
      }
    }
  }
}

// ---- GCN layer 1 aggregation fused with gemm2: one wave per node ----
// gather+reduce h (fp32, regs) -> per-wave LDS transpose -> hw2 = h @ W2
// Tail uses 4/2/1 batches: worst-case serial dependent chain 3 (was 7).
__global__ void k_agg1g2(const ushort_t* __restrict__ xw1, const int* __restrict__ row_start,
                         const int2* __restrict__ csr8, const float* __restrict__ dinv,
                         const float* __restrict__ b1, const float* __restrict__ W2,
                         float* __restrict__ hw2, int n) {
  __shared__ float2 hsm[4][64];  // per-wave h row (128 f32)
  int wid = threadIdx.x >> 6;
  int v = blockIdx.x * 4 + wid;
  if (v >= n) return;
  int lane = threadIdx.x & 63;
  float dv = dinv[v];
  unsigned sv = ((const unsigned*)(xw1 + (size_t)v * H))[lane];
  float ax = dv * bflo(sv), ay = dv * bfhi(sv);  // self-loop term
  int j0 = row_start[v], j1 = row_start[v + 1];
  int j = j0;
  for (; j + 8 <= j1; j += 8) {
    int2 ee[8];
    unsigned rr[8];
#pragma unroll
    for (int u = 0; u < 8; u++) ee[u] = csr8[j + u];
#pragma unroll
    for (int u = 0; u < 8; u++)
      rr[u] = ((const unsigned*)(xw1 + (size_t)ee[u].x * H))[lane];
#pragma unroll
    for (int u = 0; u < 8; u++) {
      float wu = __int_as_float(ee[u].y);
      ax += wu * bflo(rr[u]);
      ay += wu * bfhi(rr[u]);
    }
  }
  if (j + 4 <= j1) {
    int2 ee[4];
    unsigned rr[4];
#pragma unroll
    for (int u = 0; u < 4; u++) ee[u] = csr8[j + u];
#pragma unroll
    for (int u = 0; u < 4; u++)
      rr[u] = ((const unsigned*)(xw1 + (size_t)ee[u].x * H))[lane];
#pragma unroll
    for (int u = 0; u < 4; u++) {
      float wu = __int_as_float(ee[u].y);
      ax += wu * bflo(rr[u]);
      ay += wu * bfhi(rr[u]);
    }
    j += 4;
  }
  if (j + 2 <= j1) {
    int2 e0 = csr8[j], e1 = csr8[j + 1];
    unsigned r0 = ((const unsigned*)(xw1 + (size_t)e0.x * H))[lane];
    unsigned r1 = ((const unsigned*)(xw1 + (size_t)e1.x * H))[lane];
    float w0 = __int_as_float(e0.y), w1 = __int_as_float(e1.y);
    ax += w0 * bflo(r0) + w1 * bflo(r1);
    ay += w0 * bfhi(r0) + w1 * bfhi(r1);
    j += 2;
  }
  if (j < j1) {
    int2 e0 = csr8[j];
    unsigned r0 = ((const unsigned*)(xw1 + (size_t)e0.x * H))[lane];
    float w0 = __int_as_float(e0.y);
    ax += w0 * bflo(r0);
    ay += w0 * bfhi(r0);
  }
  int c2 = lane * 2;
  float o0 = fmaxf(dv * ax + b1[c2], 0.0f);
  float o1 = fmaxf(dv * ay + b1[c2 + 1], 0.0f);
  hsm[wid][lane] = make_float2(o0, o1);  // h[2*lane], h[2*lane+1]

  // gemm2: lane (c = lane&15, g = lane>>4) covers k in [32g, 32g+32)
  int c = lane & 15, g = lane >> 4;
  const float* hrow = (const float*)hsm[wid];  // same-wave LDS RAW (lgkmcnt)
  float p = 0.0f;
#pragma unroll
  for (int jj = 0; jj < 32; jj++)
    p += hrow[g * 32 + jj] * W2[(g * 32 + jj) * C + c];
  p += __shfl_xor(p, 16);
  p += __shfl_xor(p, 32);
  if (g == 0) hw2[(size_t)v * C + c] = p;
}

// ---- GCN layer 2 agg + log_softmax + fused decode partials A[v],B[v] ----
__global__ void k_agg2ab(const float* __restrict__ hw2, const int* __restrict__ row_start,
                         const int2* __restrict__ csr8, const float* __restrict__ dinv,
                         const float* __restrict__ b2, const int* __restrict__ y,
                         const int* __restrict__ tmask, const float* __restrict__ xe,
                         const float* __restrict__ Wd, float* __restrict__ ylp_out,
                         float* __restrict__ Aarr, float* __restrict__ Barr, int n) {
  int idx = blockIdx.x * 256 + threadIdx.x;
  int node = idx >> 4, c = idx & 15;
  if (node >= n) return;
  float dv = dinv[node];
  float acc = dv * hw2[(size_t)node * C + c];
  int j0 = row_start[node], j1 = row_start[node + 1];
  int j = j0;
  for (; j + 8 <= j1; j += 8) {
    int2 ee[8];
    float rr[8];
#pragma unroll
    for (int u = 0; u < 8; u++) ee[u] = csr8[j + u];
#pragma unroll
    for (int u = 0; u < 8; u++) rr[u] = hw2[(size_t)ee[u].x * C + c];
#pragma unroll
    for (int u = 0; u < 8; u++) acc += __int_as_float(ee[u].y) * rr[u];
  }
  if (j + 4 <= j1) {
    int2 e0 = csr8[j], e1 = csr8[j + 1], e2 = csr8[j + 2], e3 = csr8[j + 3];
    float r0 = hw2[(size_t)e0.x * C + c];
    float r1 = hw2[(size_t)e1.x * C + c];
    float r2 = hw2[(size_t)e2.x * C + c];
    float r3 = hw2[(size_t)e3.x * C + c];
    acc += __int_as_float(e0.y) * r0 + __int_as_float(e1.y) * r1 +
           __int_as_float(e2.y) * r2 + __int_as_float(e3.y) * r3;
    j += 4;
  }
  if (j + 2 <= j1) {
    int2 e0 = csr8[j], e1 = csr8[j + 1];
    float r0 = hw2[(size_t)e0.x * C + c];
    float r1 = hw2[(size_t)e1.x * C + c];
    acc += __int_as_float(e0.y) * r0 + __int_as_float(e1.y) * r1;
    j += 2;
  }
  if (j < j1) {
    int2 e0 = csr8[j];
    acc += __int_as_float(e0.y) * hw2[(size_t)e0.x * C + c];
  }
  float logit = dv * acc + b2[c];  // TEMP == 1.0
  float m = logit;
  for (int o = 8; o > 0; o >>= 1) m = fmaxf(m, __shfl_xor(m, o, 16));
  float e = expf(logit - m);
  float s16 = e;
  for (int o = 8; o > 0; o >>= 1) s16 += __shfl_xor(s16, o, 16);
  float lp = (logit - m) - logf(s16);
  ylp_out[(size_t)node * C + c] = lp;
  float yp = tmask[node] ? ((y[node] == c) ? 1.0f : 0.0f) : (e / s16);

  // decode partials: A[v] = xe[v].Wd[0:64] + yp.Wd[128:144]
  //                  B[v] = xe[v].Wd[64:128] + yp.Wd[144:160]
  float4 xv = *(const float4*)(xe + (size_t)node * HX + c * 4);
  float4 wa = *(const float4*)(Wd + c * 4);
  float4 wb = *(const float4*)(Wd + HX + c * 4);
  float pa = xv.x * wa.x + xv.y * wa.y + xv.z * wa.z + xv.w * wa.w + yp * Wd[2 * HX + c];
  float pb = xv.x * wb.x + xv.y * wb.y + xv.z * wb.z + xv.w * wb.w + yp * Wd[2 * HX + C + c];
  for (int o = 8; o > 0; o >>= 1) {
    pa += __shfl_xor(pa, o, 16);
    pb += __shfl_xor(pb, o, 16);
  }
  if (c == 0) { Aarr[node] = pa; Barr[node] = pb; }
}

// ---- edge decode: out = A[s] + B[d] + bd ; 2 edges/thread when e even ----
__global__ void k_decode(const int* __restrict__ ei, const int* __restrict__ nei,
                         const float* __restrict__ Aarr, const float* __restrict__ Barr,
                         const float* __restrict__ bd, float* __restrict__ out, int e) {
  float b0 = bd[0];
  if ((e & 1) == 0) {
    int half = e >> 1;
    int i = blockIdx.x * 256 + threadIdx.x;
    if (i >= 2 * half) return;
    if (i < half) {
      int j = 2 * i;
      int2 s2 = *(const int2*)(ei + j);
      int2 d2 = *(const int2*)(ei + e + j);
      *(float2*)(out + j) =
          make_float2(Aarr[s2.x] + Barr[d2.x] + b0, Aarr[s2.y] + Barr[d2.y] + b0);
    } else {
      int j = 2 * (i - half);
      int2 s2 = *(const int2*)(nei + j);
      int2 d2 = *(const int2*)(nei + e + j);
      *(float2*)(out + e + j) =
          make_float2(Aarr[s2.x] + Barr[d2.x] + b0, Aarr[s2.y] + Barr[d2.y] + b0);
    }
  } else {
    int i = blockIdx.x * 256 + threadIdx.x;
    if (i >= 2 * e) return;
    if (i < e) {
      out[i] = Aarr[ei[i]] + Barr[ei[e + i]] + b0;
    } else {
      int j = i - e;
      out[e + j] = Aarr[nei[j]] + Barr[nei[e + j]] + b0;
    }
  }
}

extern "C" void kernel_launch(void* const* d_in, const int* in_sizes, int n_in,
                              void* d_out, int out_size, void* d_ws, size_t ws_size,
                              hipStream_t stream) {
  const float* x = (const float*)d_in[0];
  const int* ei = (const int*)d_in[1];
  const int* nei = (const int*)d_in[2];
  const int* y = (const int*)d_in[3];
  const int* tmask = (const int*)d_in[4];
  const float* W1 = (const float*)d_in[5];
  const float* b1 = (const float*)d_in[6];
  const float* W2 = (const float*)d_in[7];
  const float* b2 = (const float*)d_in[8];
  const float* Wx = (const float*)d_in[9];
  const float* bx = (const float*)d_in[10];
  const float* Wd = (const float*)d_in[11];
  const float* bd = (const float*)d_in[12];
  float* out = (float*)d_out;

  int n = in_sizes[3];        // N nodes
  int e = in_sizes[1] / 2;    // E edges
  int ntiles = (n + 15) / 16;

  char* ws = (char*)d_ws;
  size_t off = 0;
  auto alloc = [&](size_t bytes) -> void* {
    void* p = ws + off;
    off += (bytes + 511) & ~(size_t)511;
    return p;
  };
  int* deg = (int*)alloc((size_t)n * 4);
  ushort_t* xb = (ushort_t*)alloc((size_t)ntiles * 16 * F * 2);  // tile-major, padded
  ushort_t* WBt = (ushort_t*)alloc((size_t)NBCOL * F * 2);
  ushort_t* xw1 = (ushort_t*)alloc((size_t)n * H * 2);   // bf16
  float* xe = (float*)alloc((size_t)n * HX * 4);
  float* hw2 = (float*)alloc((size_t)n * C * 4);
  float* dinv = (float*)alloc((size_t)n * 4);
  int* row_start = (int*)alloc((size_t)(n + 1) * 4);
  int* cursor = (int*)alloc((size_t)n * 4);
  int2* csr8 = (int2*)alloc((size_t)e * 8);
  float* Aarr = (float*)alloc((size_t)n * 4);
  float* Barr = (float*)alloc((size_t)n * 4);

  const int* src = ei;
  const int* dst = ei + e;

  hipMemsetAsync(deg, 0, (size_t)n * 4, stream);

  int totalU = ntiles * 512;           // 16B units of xb
  int nbx = (totalU + 255) / 256;
  int nbw = (NBCOL * F + 255) / 256;
  int nbe = (e + 255) / 256;
  k_pre<<<nbx + nbw + nbe, 256, 0, stream>>>(x, xb, totalU, W1, Wx, WBt, dst, deg, e,
                                             n, nbx, nbw);

  int nchunk = (n + 255) / 256;
  k_scan<<<nchunk, 256, 0, stream>>>(deg, row_start, cursor, dinv, n, e);
  k_fill<<<(e + 255) / 256, 256, 0, stream>>>(src, dst, dinv, cursor, csr8, e);

  int ggrid = ntiles < 768 ? ntiles : 768;
  k_gemm1<<<ggrid, 256, 0, stream>>>(xb, WBt, bx, xw1, xe, n, ntiles);
  k_agg1g2<<<(n + 3) / 4, 256, 0, stream>>>(xw1, row_start, csr8, dinv, b1, W2, hw2, n);
  k_agg2ab<<<(n * 16 + 255) / 256, 256, 0, stream>>>(hw2, row_start, csr8, dinv, b2, y,
                                                     tmask, xe, Wd, out + (size_t)2 * e,
                                                     Aarr, Barr, n);
  int dthreads = ((e & 1) == 0) ? e : 2 * e;  // 2 edges/thread when e even
  k_decode<<<(dthreads + 255) / 256, 256, 0, stream>>>(ei, nei, Aarr, Barr, bd, out, e);
}

// Round 15
// 252.710 us; speedup vs baseline: 1.0643x; 1.0643x over previous
//
#include <hip/hip_runtime.h>

typedef unsigned short ushort_t;
typedef __attribute__((ext_vector_type(8))) short short8;
typedef __attribute__((ext_vector_type(4))) float floatx4;

constexpr int F = 256, H = 128, C = 16, HX = 64;
constexpr int NBCOL = H + HX; // 192 fused output cols of GEMM1

__device__ __forceinline__ ushort_t f2bf(float f) {
  unsigned u = __float_as_uint(f);
  u += 0x7fffu + ((u >> 16) & 1u);   // round-to-nearest-even
  return (ushort_t)(u >> 16);
}
__device__ __forceinline__ float bflo(unsigned u) { return __uint_as_float(u << 16); }
__device__ __forceinline__ float bfhi(unsigned u) { return __uint_as_float(u & 0xffff0000u); }

// ---- fat pre-kernel: conv_x(tile-major) | conv_w | count ----
// xb layout: 16B unit index = tile*512 + j*16 + l15  (j = k-chunk 0..31,
// l15 = row within tile). gemm1's wave load (kk,q) then covers one
// CONTIGUOUS 1KB segment (vs 16 scattered 64B segments in row-major).
__global__ void k_pre(const float* __restrict__ x, ushort_t* __restrict__ xb, int totalU,
                      const float* __restrict__ W1, const float* __restrict__ Wx,
                      ushort_t* __restrict__ WBt,
                      const int* __restrict__ dst, int* __restrict__ deg, int e,
                      int n, int nbx, int nbw) {
  int b = blockIdx.x;
  if (b < nbx) {
    int i = b * 256 + threadIdx.x;   // 16B-unit index
    if (i >= totalU) return;
    int tile = i >> 9, rem = i & 511, j = rem >> 4, l15 = rem & 15;
    int row = tile * 16 + l15;
    ushort4 lo = make_ushort4(0, 0, 0, 0), hi = lo;
    if (row < n) {
      const float4* xp = (const float4*)(x + (size_t)row * F + j * 8);
      float4 a = xp[0], bb = xp[1];
      lo = make_ushort4(f2bf(a.x), f2bf(a.y), f2bf(a.z), f2bf(a.w));
      hi = make_ushort4(f2bf(bb.x), f2bf(bb.y), f2bf(bb.z), f2bf(bb.w));
    }
    ((ushort4*)xb)[2 * i] = lo;      // writes: perfectly coalesced
    ((ushort4*)xb)[2 * i + 1] = hi;
  } else if (b < nbx + nbw) {
    int i = (b - nbx) * 256 + threadIdx.x;
    if (i >= NBCOL * F) return;
    int nn = i / F, k = i % F;
    float v = (nn < H) ? W1[k * H + nn] : Wx[k * HX + (nn - H)];
    WBt[nn * F + k] = f2bf(v);
  } else {
    int i = (b - nbx - nbw) * 256 + threadIdx.x;
    if (i < e) atomicAdd(&deg[dst[i]], 1);
  }
}

// ---- scan step a: per-block sums ----
__global__ void k_scan_a(const int* __restrict__ deg, int* __restrict__ part, int n) {
  __shared__ int sm[256];
  int i = blockIdx.x * 256 + threadIdx.x;
  int v = (i < n) ? deg[i] : 0;
  sm[threadIdx.x] = v;
  __syncthreads();
  for (int s = 128; s > 0; s >>= 1) {
    if (threadIdx.x < s) sm[threadIdx.x] += sm[threadIdx.x + s];
    __syncthreads();
  }
  if (threadIdx.x == 0) part[blockIdx.x] = sm[0];
}

// ---- scan step c (scan_b folded in): each block sums part[0..c) itself ----
__global__ void k_scan_c(const int* __restrict__ deg, const int* __restrict__ part,
                         int* __restrict__ row_start, int* __restrict__ cursor,
                         float* __restrict__ dinv, int n, int e) {
  __shared__ int psm[256];
  __shared__ int wsum[4], woff[4];
  int c = blockIdx.x, t = threadIdx.x;
  // exclusive block offset: sum of part[0..c)  (c <= 256)
  psm[t] = (t < c) ? part[t] : 0;
  __syncthreads();
  for (int s = 128; s > 0; s >>= 1) {
    if (t < s) psm[t] += psm[t + s];
    __syncthreads();
  }
  int blockoff = psm[0];
  __syncthreads();

  int i = c * 256 + t;
  int lane = t & 63, wid = t >> 6;
  int v = (i < n) ? deg[i] : 0;
  int xs = v;
  for (int d = 1; d < 64; d <<= 1) {
    int u = __shfl_up(xs, d);
    if (lane >= d) xs += u;
  }
  if (lane == 63) wsum[wid] = xs;
  __syncthreads();
  if (t == 0) {
    int s = 0;
    for (int w = 0; w < 4; w++) { woff[w] = s; s += wsum[w]; }
  }
  __syncthreads();
  int excl = xs - v + woff[wid] + blockoff;
  if (i < n) {
    row_start[i] = excl;
    cursor[i] = excl;
    dinv[i] = rsqrtf((float)(v + 1));  // +1 self-loop
  }
  if (i == 0) row_start[n] = e;
}

// ---- CSR fill: pack (src, dinv[src]) per edge slot ----
__global__ void k_fill(const int* __restrict__ src, const int* __restrict__ dst,
                       const float* __restrict__ dinv, int* __restrict__ cursor,
                       int2* __restrict__ csr8, int e) {
  int i = blockIdx.x * 256 + threadIdx.x;
  if (i < e) {
    int s = src[i];
    int p = atomicAdd(&cursor[dst[i]], 1);
    csr8[p] = make_int2(s, __float_as_int(dinv[s]));
  }
}

// ---- MFMA GEMM, register-resident B, tile-major bf16 xb input ----
// B = 192x256 bf16 = 96 KB = 24 short8/wave @48 cols/wave, hoisted once.
// A: tile-major xb -> each of the 8 per-tile loads is one contiguous 1KB
// wave segment (whole tile A = 8KB contiguous). Total live ~160 VGPR fits
// (256,3). DO NOT read f32 x directly (R11: allocator sinks B, VGPR=72)
// and DO NOT merge into branchy fat kernels (R10: same collapse).
__global__ __launch_bounds__(256, 3) void k_gemm1(const ushort_t* __restrict__ xb,
                                                  const ushort_t* __restrict__ WBt,
                                                  const float* __restrict__ bx,
                                                  ushort_t* __restrict__ xw1,
                                                  float* __restrict__ xe,
                                                  int n, int ntiles) {
  int w = threadIdx.x >> 6, lane = threadIdx.x & 63;
  int q = lane >> 4, l15 = lane & 15;
  const short8* bb = (const short8*)WBt;
  short8 bfr[3][8];
#pragma unroll
  for (int t = 0; t < 3; t++)
#pragma unroll
    for (int kk = 0; kk < 8; kk++)
      bfr[t][kk] = bb[(size_t)(w * 48 + t * 16 + l15) * 32 + kk * 4 + q];

  float bxv[3];
#pragma unroll
  for (int t = 0; t < 3; t++) {
    int g = w * 48 + t * 16;
    bxv[t] = (g >= H) ? bx[g - H + l15] : 0.0f;
  }

  const short8* ab = (const short8*)xb;
  for (int tile = blockIdx.x; tile < ntiles; tile += gridDim.x) {
    const short8* atile = ab + (size_t)tile * 512;
    short8 a[8];
#pragma unroll
    for (int kk = 0; kk < 8; kk++) a[kk] = atile[kk * 64 + q * 16 + l15];

    floatx4 acc0 = (floatx4)(0.0f), acc1 = (floatx4)(0.0f), acc2 = (floatx4)(0.0f);
#pragma unroll
    for (int kk = 0; kk < 8; kk++) {
      acc0 = __builtin_amdgcn_mfma_f32_16x16x32_bf16(a[kk], bfr[0][kk], acc0, 0, 0, 0);
      acc1 = __builtin_amdgcn_mfma_f32_16x16x32_bf16(a[kk], bfr[1][kk], acc1, 0, 0, 0);
      acc2 = __builtin_amdgcn_mfma_f32_16x16x32_bf16(a[kk], bfr[2][kk], acc2, 0, 0, 0);
    }

    // C/D layout: col = lane&15, row = (lane>>4)*4 + r
    floatx4 accs[3] = {acc0, acc1, acc2};
    int rbase = tile * 16 + q * 4;
#pragma unroll
    for (int t = 0; t < 3; t++) {
      int g = w * 48 + t * 16;  // wave-uniform output col base
#pragma unroll
      for (int r = 0; r < 4; r++) {
        int ro = rbase + r;
        if (ro < n) {
          if (g < H) {
            xw1[(size_t)ro * H + g + l15] = f2bf(accs[t][r]);
          } else {
            xe[(size_t)ro * HX + (g - H) + l15] = fmaxf(accs[t][r] + bxv[t], 0.0f);
          }
        }
      }
    }
  }
}

// ---- GCN layer 1 aggregation fused with gemm2: one wave per node ----
// gather+reduce h (fp32, regs) -> per-wave LDS transpose -> hw2 = h @ W2
__global__ void k_agg1g2(const ushort_t* __restrict__ xw1, const int* __restrict__ row_start,
                         const int2* __restrict__ csr8, const float* __restrict__ dinv,
                         const float* __restrict__ b1, const float* __restrict__ W2,
                         float* __restrict__ hw2, int n) {
  __shared__ float2 hsm[4][64];  // per-wave h row (128 f32)
  int wid = threadIdx.x >> 6;
  int v = blockIdx.x * 4 + wid;
  if (v >= n) return;
  int lane = threadIdx.x & 63;
  float dv = dinv[v];
  unsigned sv = ((const unsigned*)(xw1 + (size_t)v * H))[lane];
  float ax = dv * bflo(sv), ay = dv * bfhi(sv);  // self-loop term
  int j0 = row_start[v], j1 = row_start[v + 1];
  int j = j0;
  for (; j + 8 <= j1; j += 8) {
    int2 ee[8];
    unsigned rr[8];
#pragma unroll
    for (int u = 0; u < 8; u++) ee[u] = csr8[j + u];
#pragma unroll
    for (int u = 0; u < 8; u++)
      rr[u] = ((const unsigned*)(xw1 + (size_t)ee[u].x * H))[lane];
#pragma unroll
    for (int u = 0; u < 8; u++) {
      float wu = __int_as_float(ee[u].y);
      ax += wu * bflo(rr[u]);
      ay += wu * bfhi(rr[u]);
    }
  }
  for (; j < j1; j++) {
    int2 e0 = csr8[j];
    unsigned r0 = ((const unsigned*)(xw1 + (size_t)e0.x * H))[lane];
    float w0 = __int_as_float(e0.y);
    ax += w0 * bflo(r0);
    ay += w0 * bfhi(r0);
  }
  int c2 = lane * 2;
  float o0 = fmaxf(dv * ax + b1[c2], 0.0f);
  float o1 = fmaxf(dv * ay + b1[c2 + 1], 0.0f);
  hsm[wid][lane] = make_float2(o0, o1);  // h[2*lane], h[2*lane+1]

  // gemm2: lane (c = lane&15, g = lane>>4) covers k in [32g, 32g+32)
  int c = lane & 15, g = lane >> 4;
  const float* hrow = (const float*)hsm[wid];  // same-wave LDS RAW (lgkmcnt)
  float p = 0.0f;
#pragma unroll
  for (int jj = 0; jj < 32; jj++)
    p += hrow[g * 32 + jj] * W2[(g * 32 + jj) * C + c];
  p += __shfl_xor(p, 16);
  p += __shfl_xor(p, 32);
  if (g == 0) hw2[(size_t)v * C + c] = p;
}

// ---- GCN layer 2 agg + log_softmax + fused decode partials A[v],B[v] ----
__global__ void k_agg2ab(const float* __restrict__ hw2, const int* __restrict__ row_start,
                         const int2* __restrict__ csr8, const float* __restrict__ dinv,
                         const float* __restrict__ b2, const int* __restrict__ y,
                         const int* __restrict__ tmask, const float* __restrict__ xe,
                         const float* __restrict__ Wd, float* __restrict__ ylp_out,
                         float* __restrict__ Aarr, float* __restrict__ Barr, int n) {
  int idx = blockIdx.x * 256 + threadIdx.x;
  int node = idx >> 4, c = idx & 15;
  if (node >= n) return;
  float dv = dinv[node];
  float acc = dv * hw2[(size_t)node * C + c];
  int j0 = row_start[node], j1 = row_start[node + 1];
  int j = j0;
  for (; j + 8 <= j1; j += 8) {
    int2 ee[8];
    float rr[8];
#pragma unroll
    for (int u = 0; u < 8; u++) ee[u] = csr8[j + u];
#pragma unroll
    for (int u = 0; u < 8; u++) rr[u] = hw2[(size_t)ee[u].x * C + c];
#pragma unroll
    for (int u = 0; u < 8; u++) acc += __int_as_float(ee[u].y) * rr[u];
  }
  for (; j + 4 <= j1; j += 4) {
    int2 e0 = csr8[j], e1 = csr8[j + 1], e2 = csr8[j + 2], e3 = csr8[j + 3];
    float r0 = hw2[(size_t)e0.x * C + c];
    float r1 = hw2[(size_t)e1.x * C + c];
    float r2 = hw2[(size_t)e2.x * C + c];
    float r3 = hw2[(size_t)e3.x * C + c];
    acc += __int_as_float(e0.y) * r0 + __int_as_float(e1.y) * r1 +
           __int_as_float(e2.y) * r2 + __int_as_float(e3.y) * r3;
  }
  for (; j < j1; j++) {
    int2 e0 = csr8[j];
    acc += __int_as_float(e0.y) * hw2[(size_t)e0.x * C + c];
  }
  float logit = dv * acc + b2[c];  // TEMP == 1.0
  float m = logit;
  for (int o = 8; o > 0; o >>= 1) m = fmaxf(m, __shfl_xor(m, o, 16));
  float e = expf(logit - m);
  float s16 = e;
  for (int o = 8; o > 0; o >>= 1) s16 += __shfl_xor(s16, o, 16);
  float lp = (logit - m) - logf(s16);
  ylp_out[(size_t)node * C + c] = lp;
  float yp = tmask[node] ? ((y[node] == c) ? 1.0f : 0.0f) : (e / s16);

  // decode partials: A[v] = xe[v].Wd[0:64] + yp.Wd[128:144]
  //                  B[v] = xe[v].Wd[64:128] + yp.Wd[144:160]
  float4 xv = *(const float4*)(xe + (size_t)node * HX + c * 4);
  float4 wa = *(const float4*)(Wd + c * 4);
  float4 wb = *(const float4*)(Wd + HX + c * 4);
  float pa = xv.x * wa.x + xv.y * wa.y + xv.z * wa.z + xv.w * wa.w + yp * Wd[2 * HX + c];
  float pb = xv.x * wb.x + xv.y * wb.y + xv.z * wb.z + xv.w * wb.w + yp * Wd[2 * HX + C + c];
  for (int o = 8; o > 0; o >>= 1) {
    pa += __shfl_xor(pa, o, 16);
    pb += __shfl_xor(pb, o, 16);
  }
  if (c == 0) { Aarr[node] = pa; Barr[node] = pb; }
}

// ---- edge decode: out = A[s] + B[d] + bd ----
__global__ void k_decode(const int* __restrict__ ei, const int* __restrict__ nei,
                         const float* __restrict__ Aarr, const float* __restrict__ Barr,
                         const float* __restrict__ bd, float* __restrict__ out, int e) {
  int i = blockIdx.x * 256 + threadIdx.x;
  if (i >= 2 * e) return;
  float b0 = bd[0];
  if (i < e) {
    int s = ei[i], d = ei[e + i];
    out[i] = Aarr[s] + Barr[d] + b0;
  } else {
    int j = i - e;
    int s = nei[j], d = nei[e + j];
    out[e + j] = Aarr[s] + Barr[d] + b0;
  }
}

extern "C" void kernel_launch(void* const* d_in, const int* in_sizes, int n_in,
                              void* d_out, int out_size, void* d_ws, size_t ws_size,
                              hipStream_t stream) {
  const float* x = (const float*)d_in[0];
  const int* ei = (const int*)d_in[1];
  const int* nei = (const int*)d_in[2];
  const int* y = (const int*)d_in[3];
  const int* tmask = (const int*)d_in[4];
  const float* W1 = (const float*)d_in[5];
  const float* b1 = (const float*)d_in[6];
  const float* W2 = (const float*)d_in[7];
  const float* b2 = (const float*)d_in[8];
  const float* Wx = (const float*)d_in[9];
  const float* bx = (const float*)d_in[10];
  const float* Wd = (const float*)d_in[11];
  const float* bd = (const float*)d_in[12];
  float* out = (float*)d_out;

  int n = in_sizes[3];        // N nodes
  int e = in_sizes[1] / 2;    // E edges
  int ntiles = (n + 15) / 16;

  char* ws = (char*)d_ws;
  size_t off = 0;
  auto alloc = [&](size_t bytes) -> void* {
    void* p = ws + off;
    off += (bytes + 511) & ~(size_t)511;
    return p;
  };
  int* deg = (int*)alloc((size_t)n * 4);
  ushort_t* xb = (ushort_t*)alloc((size_t)ntiles * 16 * F * 2);  // tile-major, padded
  ushort_t* WBt = (ushort_t*)alloc((size_t)NBCOL * F * 2);
  ushort_t* xw1 = (ushort_t*)alloc((size_t)n * H * 2);   // bf16
  float* xe = (float*)alloc((size_t)n * HX * 4);
  float* hw2 = (float*)alloc((size_t)n * C * 4);
  float* dinv = (float*)alloc((size_t)n * 4);
  int* row_start = (int*)alloc((size_t)(n + 1) * 4);
  int* cursor = (int*)alloc((size_t)n * 4);
  int2* csr8 = (int2*)alloc((size_t)e * 8);
  int* part = (int*)alloc(1024 * 4);
  float* Aarr = (float*)alloc((size_t)n * 4);
  float* Barr = (float*)alloc((size_t)n * 4);

  const int* src = ei;
  const int* dst = ei + e;

  hipMemsetAsync(deg, 0, (size_t)n * 4, stream);

  int totalU = ntiles * 512;           // 16B units of xb
  int nbx = (totalU + 255) / 256;
  int nbw = (NBCOL * F + 255) / 256;
  int nbe = (e + 255) / 256;
  k_pre<<<nbx + nbw + nbe, 256, 0, stream>>>(x, xb, totalU, W1, Wx, WBt, dst, deg, e,
                                             n, nbx, nbw);

  int nchunk = (n + 255) / 256;  // 196 <= 256, required by folded scan
  k_scan_a<<<nchunk, 256, 0, stream>>>(deg, part, n);
  k_scan_c<<<nchunk, 256, 0, stream>>>(deg, part, row_start, cursor, dinv, n, e);
  k_fill<<<(e + 255) / 256, 256, 0, stream>>>(src, dst, dinv, cursor, csr8, e);

  int ggrid = ntiles < 768 ? ntiles : 768;
  k_gemm1<<<ggrid, 256, 0, stream>>>(xb, WBt, bx, xw1, xe, n, ntiles);
  k_agg1g2<<<(n + 3) / 4, 256, 0, stream>>>(xw1, row_start, csr8, dinv, b1, W2, hw2, n);
  k_agg2ab<<<(n * 16 + 255) / 256, 256, 0, stream>>>(hw2, row_start, csr8, dinv, b2, y,
                                                     tmask, xe, Wd, out + (size_t)2 * e,
                                                     Aarr, Barr, n);
  k_decode<<<(2 * e + 255) / 256, 256, 0, stream>>>(ei, nei, Aarr, Barr, bd, out, e);
}